// Round 9
// baseline (490.679 us; speedup 1.0000x reference)
//
#include <hip/hip_runtime.h>

static constexpr float NEG_SLOPE = 0.01f;
static constexpr float BN_EPS = 1e-5f;

using f16 = _Float16;
using f16x2 = __attribute__((ext_vector_type(2))) _Float16;
using f16x4 = __attribute__((ext_vector_type(4))) _Float16;
using f32x4 = __attribute__((ext_vector_type(4))) float;

// ---------------------------------------------------------------------------
__global__ __launch_bounds__(256) void sentinel_kernel(float* out, int m, float val) {
  int i = blockIdx.x * 256 + threadIdx.x;
  if (i < m) out[i] = val;
}

// zero deg (n ints) + stats (256 floats) + the zero-row of g (row n, 128 B)
__global__ __launch_bounds__(256) void zero_kernel(int* __restrict__ deg,
                                                   float* __restrict__ stats,
                                                   unsigned int* __restrict__ gzero, int n) {
  int stride = gridDim.x * blockDim.x;
  for (int i = blockIdx.x * blockDim.x + threadIdx.x; i < n; i += stride) deg[i] = 0;
  if (blockIdx.x == 0 && threadIdx.x < 256) stats[threadIdx.x] = 0.f;
  if (blockIdx.x == 0 && threadIdx.x < 32) gzero[threadIdx.x] = 0u;
}

// deg[v] += 1 per incoming edge; 4 independent edges per thread
__global__ __launch_bounds__(256) void deg_kernel(const int* __restrict__ col,
                                                  int* __restrict__ deg, int E) {
  int t = blockIdx.x * 256 + threadIdx.x;
  int S = gridDim.x * 256;
  int e0 = t, e1 = t + S, e2 = t + 2 * S, e3 = t + 3 * S;
  int v0 = (e0 < E) ? col[e0] : -1;
  int v1 = (e1 < E) ? col[e1] : -1;
  int v2 = (e2 < E) ? col[e2] : -1;
  int v3 = (e3 < E) ? col[e3] : -1;
  if (v0 >= 0) atomicAdd(&deg[v0], 1);
  if (v1 >= 0) atomicAdd(&deg[v1], 1);
  if (v2 >= 0) atomicAdd(&deg[v2], 1);
  if (v3 >= 0) atomicAdd(&deg[v3], 1);
}

// ---------------------------------------------------------------------------
// 3-phase exclusive scan over PADDED degrees pd=(deg+15)&~15 -> pstart,
// cursor[v]=pstart[v]+deg (fill countdown), dis=rsqrt(deg+1), pad slots -> n.
__global__ __launch_bounds__(256) void scan_partial(const int* __restrict__ deg,
                                                    int* __restrict__ partial, int n) {
  int i = blockIdx.x * 256 + threadIdx.x;
  int d = (i < n) ? deg[i] : 0;
  int pd = (d + 15) & ~15;
  __shared__ int s[256];
  s[threadIdx.x] = pd;
  __syncthreads();
  for (int off = 128; off; off >>= 1) {
    if (threadIdx.x < off) s[threadIdx.x] += s[threadIdx.x + off];
    __syncthreads();
  }
  if (threadIdx.x == 0) partial[blockIdx.x] = s[0];
}

__global__ __launch_bounds__(256) void scan_top(int* partial, int nb) {
  __shared__ int s[256];
  __shared__ int carry_s;
  if (threadIdx.x == 0) carry_s = 0;
  __syncthreads();
  for (int base = 0; base < nb; base += 256) {
    int i = base + threadIdx.x;
    int v = (i < nb) ? partial[i] : 0;
    s[threadIdx.x] = v;
    __syncthreads();
    for (int off = 1; off < 256; off <<= 1) {
      int t = (threadIdx.x >= off) ? s[threadIdx.x - off] : 0;
      __syncthreads();
      s[threadIdx.x] += t;
      __syncthreads();
    }
    int inc = s[threadIdx.x];
    int tot = s[255];
    int carry = carry_s;
    if (i < nb) partial[i] = carry + inc - v;
    __syncthreads();
    if (threadIdx.x == 0) carry_s = carry + tot;
    __syncthreads();
  }
}

__global__ __launch_bounds__(256) void scan_final(const int* __restrict__ deg,
                                                  const int* __restrict__ partial,
                                                  int* __restrict__ pstart,
                                                  int* __restrict__ cursor,
                                                  int* __restrict__ csr,
                                                  float* __restrict__ dis, int n) {
  int i = blockIdx.x * 256 + threadIdx.x;
  int d = (i < n) ? deg[i] : 0;
  int pd = (d + 15) & ~15;
  __shared__ int s[256];
  s[threadIdx.x] = pd;
  __syncthreads();
  for (int off = 1; off < 256; off <<= 1) {
    int t = (threadIdx.x >= off) ? s[threadIdx.x - off] : 0;
    __syncthreads();
    s[threadIdx.x] += t;
    __syncthreads();
  }
  if (i < n) {
    int incl = partial[blockIdx.x] + s[threadIdx.x];
    int ps = incl - pd;
    pstart[i] = ps;
    cursor[i] = ps + d;
    dis[i] = rsqrtf((float)(d + 1));
    for (int j = d; j < pd; ++j) csr[ps + j] = n;  // pad -> zero row
    if (i == n - 1) pstart[n] = incl;
  }
}

// csr[--cursor[v]] = row[e]; 4 independent edges per thread
__global__ __launch_bounds__(256) void fill_kernel(
    const int* __restrict__ row, const int* __restrict__ colv,
    int* __restrict__ cursor, int* __restrict__ csr, int E) {
  int t = blockIdx.x * 256 + threadIdx.x;
  int S = gridDim.x * 256;
  int e0 = t, e1 = t + S, e2 = t + 2 * S, e3 = t + 3 * S;
  bool b0 = e0 < E, b1 = e1 < E, b2 = e2 < E, b3 = e3 < E;
  int v0 = 0, v1 = 0, v2 = 0, v3 = 0, r0 = 0, r1 = 0, r2 = 0, r3 = 0;
  if (b0) { v0 = colv[e0]; r0 = row[e0]; }
  if (b1) { v1 = colv[e1]; r1 = row[e1]; }
  if (b2) { v2 = colv[e2]; r2 = row[e2]; }
  if (b3) { v3 = colv[e3]; r3 = row[e3]; }
  int o0 = 0, o1 = 0, o2 = 0, o3 = 0;
  if (b0) o0 = atomicSub(&cursor[v0], 1) - 1;
  if (b1) o1 = atomicSub(&cursor[v1], 1) - 1;
  if (b2) o2 = atomicSub(&cursor[v2], 1) - 1;
  if (b3) o3 = atomicSub(&cursor[v3], 1) - 1;
  if (b0) csr[o0] = r0;
  if (b1) csr[o1] = r1;
  if (b2) csr[o2] = r2;
  if (b3) csr[o3] = r3;
}

// ---------------------------------------------------------------------------
// MFMA GEMM: g[r,c] = ((A[r,:](*sc) @ W[:,c]) + cadd[c]) * dis[r], fp16 out.
template <int KD, bool FOLD, bool A_HALF>
__global__ __launch_bounds__(256) void mfma_gemm(
    const void* __restrict__ Aptr, const float* __restrict__ W,
    const float* __restrict__ sc, const float* __restrict__ cadd,
    const float* __restrict__ dis, f16* __restrict__ g, int n) {
  constexpr int NKT = KD / 16;
  const int lane = threadIdx.x & 63;
  const int wq = threadIdx.x >> 6;
  const int lr = lane & 15;
  const int kb = (lane >> 4) * 4;

  f16x4 bfrag[NKT][4];
#pragma unroll
  for (int kt = 0; kt < NKT; ++kt)
#pragma unroll
    for (int ct = 0; ct < 4; ++ct) {
#pragma unroll
      for (int j = 0; j < 4; ++j) {
        int k = kt * 16 + kb + j;
        float w = W[k * 64 + ct * 16 + lr];
        if (FOLD) w *= sc[k];
        bfrag[kt][ct][j] = (f16)w;
      }
    }
  float cl[4];
#pragma unroll
  for (int ct = 0; ct < 4; ++ct) cl[ct] = FOLD ? cadd[ct * 16 + lr] : 0.f;

  const int ntiles = (n + 15) >> 4;
  for (int t = blockIdx.x * 4 + wq; t < ntiles; t += gridDim.x * 4) {
    const int r0 = t << 4;
    int arow = r0 + lr;
    if (arow >= n) arow = n - 1;
    f16x4 afrag[NKT];
    if (A_HALF) {
      const f16* Ah = (const f16*)Aptr;
#pragma unroll
      for (int kt = 0; kt < NKT; ++kt)
        afrag[kt] = *reinterpret_cast<const f16x4*>(Ah + (size_t)arow * KD + kt * 16 + kb);
    } else {
      const float* Af = (const float*)Aptr;
#pragma unroll
      for (int kt = 0; kt < NKT; ++kt) {
        f32x4 xa = *reinterpret_cast<const f32x4*>(Af + (size_t)arow * KD + kt * 16 + kb);
        f16x4 a;
        a[0] = (f16)xa[0]; a[1] = (f16)xa[1]; a[2] = (f16)xa[2]; a[3] = (f16)xa[3];
        afrag[kt] = a;
      }
    }
    f32x4 acc[4];
#pragma unroll
    for (int ct = 0; ct < 4; ++ct) acc[ct] = (f32x4){0.f, 0.f, 0.f, 0.f};
#pragma unroll
    for (int kt = 0; kt < NKT; ++kt)
#pragma unroll
      for (int ct = 0; ct < 4; ++ct)
        acc[ct] = __builtin_amdgcn_mfma_f32_16x16x16f16(afrag[kt], bfrag[kt][ct], acc[ct], 0, 0, 0);
    if (r0 + 16 <= n) {
#pragma unroll
      for (int v = 0; v < 4; ++v) {
        int grow = r0 + (lane >> 4) * 4 + v;
        float dv = dis[grow];
#pragma unroll
        for (int ct = 0; ct < 4; ++ct)
          g[(size_t)grow * 64 + ct * 16 + lr] = (f16)((acc[ct][v] + cl[ct]) * dv);
      }
    } else {
      for (int v = 0; v < 4; ++v) {
        int grow = r0 + (lane >> 4) * 4 + v;
        if (grow < n) {
          float dv = dis[grow];
          for (int ct = 0; ct < 4; ++ct)
            g[(size_t)grow * 64 + ct * 16 + lr] = (f16)((acc[ct][v] + cl[ct]) * dv);
        }
      }
    }
  }
}

// ---------------------------------------------------------------------------
// t[v] = leaky(dis[v]*(g[v] + sum_{u in CSRp[v]} g[u]) + bias); stats sum/sumsq.
// 32 lanes per node (lane=feature pair, f16x2); one wave = 2 nodes; CSR lists
// padded to x16 with zero-row index n -> no masking VALU in the inner loop.
template <int HOUT>
__global__ __launch_bounds__(256) void gather_post2(
    const f16* __restrict__ g, const int* __restrict__ csr,
    const int* __restrict__ pstart, const float* __restrict__ dis,
    const float* __restrict__ bias, void* __restrict__ t_out,
    float* __restrict__ stats, int n) {
  const int tid = threadIdx.x;
  const int fl = tid & 31;            // feature-pair index
  const int half = (tid >> 5) & 1;
  const float2 bd = reinterpret_cast<const float2*>(bias)[fl];
  const f16x2* __restrict__ g2 = reinterpret_cast<const f16x2*>(g);
  const int wid = (blockIdx.x * 256 + tid) >> 6;
  const int nw = (gridDim.x * 256) >> 6;
  float sx = 0.f, sy = 0.f, qx = 0.f, qy = 0.f;
  for (int v = wid * 2 + half; v < n; v += nw * 2) {
    const int ps = pstart[v];
    const int pe = pstart[v + 1];
    f16x2 sv = g2[v * 32 + fl];  // self loop
    float ax = (float)sv[0], ay = (float)sv[1];
    for (int e = ps; e < pe; e += 16) {
      const int4* c4 = reinterpret_cast<const int4*>(csr + e);
      int4 ua = c4[0], ub = c4[1], uc = c4[2], ud = c4[3];
      f16x2 d0 = g2[ua.x * 32 + fl], d1 = g2[ua.y * 32 + fl];
      f16x2 d2 = g2[ua.z * 32 + fl], d3 = g2[ua.w * 32 + fl];
      f16x2 d4 = g2[ub.x * 32 + fl], d5 = g2[ub.y * 32 + fl];
      f16x2 d6 = g2[ub.z * 32 + fl], d7 = g2[ub.w * 32 + fl];
      f16x2 d8 = g2[uc.x * 32 + fl], d9 = g2[uc.y * 32 + fl];
      f16x2 da = g2[uc.z * 32 + fl], db = g2[uc.w * 32 + fl];
      f16x2 dc = g2[ud.x * 32 + fl], dd = g2[ud.y * 32 + fl];
      f16x2 de = g2[ud.z * 32 + fl], df = g2[ud.w * 32 + fl];
      float px = (((float)d0[0] + (float)d1[0]) + ((float)d2[0] + (float)d3[0])) +
                 (((float)d4[0] + (float)d5[0]) + ((float)d6[0] + (float)d7[0])) +
                 (((float)d8[0] + (float)d9[0]) + ((float)da[0] + (float)db[0])) +
                 (((float)dc[0] + (float)dd[0]) + ((float)de[0] + (float)df[0]));
      float py = (((float)d0[1] + (float)d1[1]) + ((float)d2[1] + (float)d3[1])) +
                 (((float)d4[1] + (float)d5[1]) + ((float)d6[1] + (float)d7[1])) +
                 (((float)d8[1] + (float)d9[1]) + ((float)da[1] + (float)db[1])) +
                 (((float)dc[1] + (float)dd[1]) + ((float)de[1] + (float)df[1]));
      ax += px;
      ay += py;
    }
    float dv = dis[v];
    float tx = dv * ax + bd.x;
    tx = (tx > 0.f) ? tx : NEG_SLOPE * tx;
    float ty = dv * ay + bd.y;
    ty = (ty > 0.f) ? ty : NEG_SLOPE * ty;
    if (HOUT) {
      f16x2 o;
      o[0] = (f16)tx;
      o[1] = (f16)ty;
      reinterpret_cast<f16x2*>(t_out)[v * 32 + fl] = o;
    } else {
      reinterpret_cast<float2*>(t_out)[v * 32 + fl] = make_float2(tx, ty);
    }
    sx += tx; sy += ty;
    qx += tx * tx; qy += ty * ty;
  }
  __shared__ float4 red[256];
  red[tid] = make_float4(sx, sy, qx, qy);
  __syncthreads();
  if (tid < 32) {
    float4 a = red[tid];
#pragma unroll
    for (int o = 32; o < 256; o += 32) {
      float4 b = red[tid + o];
      a.x += b.x; a.y += b.y; a.z += b.z; a.w += b.w;
    }
    atomicAdd(&stats[2 * tid], a.x);
    atomicAdd(&stats[2 * tid + 1], a.y);
    atomicAdd(&stats[64 + 2 * tid], a.z);
    atomicAdd(&stats[64 + 2 * tid + 1], a.w);
  }
}

// ---------------------------------------------------------------------------
// BN fold params: sc[d]=gamma*rstd, sh[d]=beta-mu*sc; if withC also
// c[j] = sum_k sh[k]*W[k,j].
__global__ __launch_bounds__(64) void bnparam_kernel(
    const float* __restrict__ stats, const float* __restrict__ gamma,
    const float* __restrict__ beta, const float* __restrict__ W,
    float* __restrict__ outp, int n, int withC) {
  int d = threadIdx.x;
  __shared__ float ssh[64];
  float inv_n = 1.0f / (float)n;
  float mu = stats[d] * inv_n;
  float var = stats[64 + d] * inv_n - mu * mu;
  float r = rsqrtf(var + BN_EPS);
  float s = gamma[d] * r;
  float sh = beta[d] - mu * s;
  outp[d] = s;
  outp[64 + d] = sh;
  ssh[d] = sh;
  __syncthreads();
  if (withC) {
    float c = 0.f;
    for (int k = 0; k < 64; ++k) c = fmaf(ssh[k], W[k * 64 + d], c);
    outp[128 + d] = c;
  }
}

// fused: h_sel = t[idx]*sc1+sh1; out2 = sigmoid(h_sel@Wm+bm)
__global__ __launch_bounds__(256) void selmlp_kernel(
    const float* __restrict__ t, const int* __restrict__ idx,
    const float* __restrict__ bnp, const float* __restrict__ Wm,
    const float* __restrict__ bm, float* __restrict__ out,
    float* __restrict__ out2, int K) {
  const int lane = threadIdx.x & 63;
  int w = (blockIdx.x * 256 + threadIdx.x) >> 6;
  if (w >= K) return;
  int v = idx[w];
  float hv = fmaf(t[(size_t)v * 64 + lane], bnp[lane], bnp[64 + lane]);
  out[(size_t)w * 64 + lane] = hv;
#pragma unroll
  for (int j = 0; j < 5; ++j) {
    float p = hv * Wm[lane * 5 + j];
#pragma unroll
    for (int off = 32; off; off >>= 1) p += __shfl_xor(p, off);
    if (lane == 0) out2[(size_t)w * 5 + j] = 1.f / (1.f + expf(-(p + bm[j])));
  }
}

// ---------------------------------------------------------------------------
extern "C" void kernel_launch(void* const* d_in, const int* in_sizes, int n_in,
                              void* d_out, int out_size, void* d_ws, size_t ws_size,
                              hipStream_t stream) {
  const float* x      = (const float*)d_in[0];
  const int*   eidx   = (const int*)d_in[1];
  const int*   idx    = (const int*)d_in[2];
  const float* W0     = (const float*)d_in[3];
  const float* b0     = (const float*)d_in[4];
  const float* gamma0 = (const float*)d_in[5];
  const float* beta0  = (const float*)d_in[6];
  const float* W1     = (const float*)d_in[7];
  const float* b1     = (const float*)d_in[8];
  const float* gamma1 = (const float*)d_in[9];
  const float* beta1  = (const float*)d_in[10];
  const float* Wm     = (const float*)d_in[11];
  const float* bm     = (const float*)d_in[12];

  const int n = in_sizes[0] / 128;
  const int E = in_sizes[1] / 2;
  const int K = in_sizes[2];
  const int* erow = eidx;      // sources  (edge_index[0])
  const int* ecol = eidx + E;  // targets  (edge_index[1])
  const int nb = (n + 255) / 256;
  const size_t Ecap = (size_t)E + 16 * (size_t)n;  // padded csr capacity

  size_t needed = (size_t)n * 64 * 4            // tf
                + ((size_t)n + 1) * 64 * 2      // gh (+zero row)
                + (size_t)n * 64 * 2            // t0h
                + (size_t)n * 4 * 3             // dis, deg, cursor
                + ((size_t)n + 4) * 4           // pstart
                + Ecap * 4                      // csr (padded)
                + 256 * 4 + 320 * 4             // stats + bnp
                + (size_t)(nb + 4) * 4;         // partial
  if (ws_size < needed) {
    sentinel_kernel<<<dim3((out_size + 255) / 256), dim3(256), 0, stream>>>(
        (float*)d_out, out_size, 1e6f);
    return;
  }
  float* tf     = (float*)d_ws;                   // n*64 f32
  f16*   gh     = (f16*)(tf + (size_t)n * 64);    // (n+1)*64 fp16
  f16*   t0h    = gh + ((size_t)n + 1) * 64;      // n*64 fp16
  float* dis    = (float*)(t0h + (size_t)n * 64); // n
  int*   deg    = (int*)(dis + n);                // n
  int*   pstart = deg + n;                        // n+4
  int*   cursor = pstart + (n + 4);               // n
  int*   csr    = cursor + n;                     // Ecap (16B-aligned)
  float* stats  = (float*)(csr + Ecap);           // 256
  float* bnp    = stats + 256;                    // 320
  int*   partial = (int*)(bnp + 320);             // nb+4

  dim3 blk(256);
  const int eb4 = (E + 1023) / 1024;
  // ---- graph preprocessing ----
  zero_kernel<<<dim3(nb), blk, 0, stream>>>(deg, stats, (unsigned int*)(gh + (size_t)n * 64), n);
  deg_kernel<<<dim3(eb4), blk, 0, stream>>>(ecol, deg, E);
  scan_partial<<<dim3(nb), blk, 0, stream>>>(deg, partial, n);
  scan_top<<<dim3(1), blk, 0, stream>>>(partial, nb);
  scan_final<<<dim3(nb), blk, 0, stream>>>(deg, partial, pstart, cursor, csr, dis, n);
  fill_kernel<<<dim3(eb4), blk, 0, stream>>>(erow, ecol, cursor, csr, E);

  // ---- layer 0 ----
  mfma_gemm<128, false, false><<<dim3(640), blk, 0, stream>>>(
      x, W0, nullptr, nullptr, dis, gh, n);
  gather_post2<1><<<dim3(2048), blk, 0, stream>>>(gh, csr, pstart, dis, b0, t0h, stats, n);
  bnparam_kernel<<<dim3(1), dim3(64), 0, stream>>>(stats, gamma0, beta0, W1, bnp, n, 1);
  // ---- layer 1 (BN0 folded into GEMM) ----
  mfma_gemm<64, true, true><<<dim3(640), blk, 0, stream>>>(
      t0h, W1, bnp, bnp + 128, dis, gh, n);
  gather_post2<0><<<dim3(2048), blk, 0, stream>>>(gh, csr, pstart, dis, b1, tf, stats + 128, n);
  bnparam_kernel<<<dim3(1), dim3(64), 0, stream>>>(
      stats + 128, gamma1, beta1, nullptr, bnp + 192, n, 0);
  // ---- select + MLP (BN1 folded in) ----
  selmlp_kernel<<<dim3((K + 3) / 4), blk, 0, stream>>>(
      tf, idx, bnp + 192, Wm, bm, (float*)d_out, (float*)d_out + (size_t)K * 64, K);
}